// Round 1
// 89.184 us; speedup vs baseline: 1.0013x; 1.0013x over previous
//
#include <hip/hip_runtime.h>
#include <math.h>

// SupConLoss reduced algebraically:
//   sum(sim)      = ||sum_i x_hat_i||^2 / T
//   sum(sim*mask) = sum_c ||S_c||^2 / T,  S_c = sum_{lab==c} x_hat_i
//   n_pos         = sum_c n_c^2
// O(N*H). Labels in [0,10). N=8192, H=768.
//
// R10: restructure back half. Old: k2 sliced the p-sum (PSLICES=8, scalar
// loads) -> k3 (1 block) re-read 245KB csum8 with ~160 scattered L3-latency
// loads/thread to finish sums before squaring. New: k2_full gives each of
// 24x512 blocks a FULL p-sum over a 32-h stripe (float4, 128B-coalesced),
// squares locally, emits 2 doubles; k3 is now histogram + 48 loads.
// Prediction: dur 89.3 -> ~84 (fill ~44us is harness-fixed; k1 untouched
// for attribution). If within +-4us noise: old back-half was already <=5us,
// residual = fill + k1 + launch overhead.
// History: 119.9 (R1) -> 94.6 (R5 register-acc k1) -> 90.5 (R7 8-deep
// phase-B MLP + PSLICES=8) -> 89.3 (R9 lock). R4 cooperative fused = 184.7;
// R6 last-block-done fence = 106.7 (device fence > dispatch boundary).

#define NCLS 10
#define HDIM 768
#define HV4  (HDIM / 4)            // 192 float4 per row
#define CLS_FLOATS (NCLS * HDIM)   // 7680
#define CLS_F4 (CLS_FLOATS / 4)    // 1920 float4 per partial block
#define HD_F4  (HDIM / 4)          // 192 float4 per class row
#define PBLK 256                   // phase-1 blocks == partial count
#define RPB  32                    // rows per block = N / PBLK
#define K2BLK 24                   // h-stripe blocks: 24 x 32 h = 768
#define K2THR 512

__global__ __launch_bounds__(768) void k1_fused(
    const float* __restrict__ x, const int* __restrict__ lab,
    float* __restrict__ partials) {
  __shared__ float srn[RPB];
  __shared__ int   slab[RPB];
  const int tid = threadIdx.x, lane = tid & 63, wave = tid >> 6;  // 12 waves
  const int row0 = blockIdx.x * RPB;
  const float4* __restrict__ x4 = (const float4*)x;

  // ---- phase A: row norms, wave-per-row ----
  for (int r = wave; r < RPB; r += 12) {
    const int row = row0 + r;
    const size_t b = (size_t)row * HV4;
    const float4 t0 = x4[b + lane];
    const float4 t1 = x4[b + 64 + lane];
    const float4 t2 = x4[b + 128 + lane];
    float ss = t0.x * t0.x + t0.y * t0.y + t0.z * t0.z + t0.w * t0.w +
               t1.x * t1.x + t1.y * t1.y + t1.z * t1.z + t1.w * t1.w +
               t2.x * t2.x + t2.y * t2.y + t2.z * t2.z + t2.w * t2.w;
#pragma unroll
    for (int off = 32; off >= 1; off >>= 1) ss += __shfl_xor(ss, off, 64);
    if (lane == 0) {
      srn[r] = 1.0f / fmaxf(sqrtf(ss), 1e-12f);  // F.normalize clamp
      slab[r] = lab[row];
    }
  }
  __syncthreads();

  // ---- phase B: one thread per h-column, register class accumulators ----
  float acc[NCLS];
#pragma unroll
  for (int c = 0; c < NCLS; ++c) acc[c] = 0.0f;

  for (int rb = 0; rb < RPB; rb += 8) {
    float v[8];
#pragma unroll
    for (int u = 0; u < 8; ++u)  // 8 independent L2-hit loads in flight
      v[u] = x[(size_t)(row0 + rb + u) * HDIM + tid];
#pragma unroll
    for (int u = 0; u < 8; ++u) {
      const float s = srn[rb + u];                                // broadcast
      const int c = __builtin_amdgcn_readfirstlane(slab[rb + u]); // uniform
      const float p = v[u] * s;
      switch (c) {  // scalar branch; acc[] stays in named VGPRs
        case 0: acc[0] += p; break;
        case 1: acc[1] += p; break;
        case 2: acc[2] += p; break;
        case 3: acc[3] += p; break;
        case 4: acc[4] += p; break;
        case 5: acc[5] += p; break;
        case 6: acc[6] += p; break;
        case 7: acc[7] += p; break;
        case 8: acc[8] += p; break;
        default: acc[9] += p; break;
      }
    }
  }

  float* __restrict__ outp = partials + (size_t)blockIdx.x * CLS_FLOATS;
#pragma unroll
  for (int c = 0; c < NCLS; ++c) outp[c * HDIM + tid] = acc[c];  // coalesced
}

// 24 blocks x 512 threads: block owns a 32-h stripe (8 float4 columns) across
// ALL 10 classes and ALL 256 partials. Full p-sum locally -> square locally.
// Thread map: f = tid&7 (float4 col within stripe), pg = tid>>3 (64 groups of
// 4 p). Wave lanes 0-7 read 8 consecutive float4 = one 128B line (aligned:
// h04*16B is a 128B multiple), lanes 8-15 the line 30720B away, etc. -> every
// wave-load is 8 perfect 128B transactions.
__global__ __launch_bounds__(K2THR) void k2_full(
    const float* __restrict__ partials, double* __restrict__ bsums) {
  const float4* __restrict__ p4 = (const float4*)partials;
  const int tid = threadIdx.x, lane = tid & 63, wave = tid >> 6;
  const int f  = tid & 7;
  const int pg = tid >> 3;               // 0..63
  const int h04 = blockIdx.x * 8;        // float4 column base

  float4 acc[NCLS];
#pragma unroll
  for (int c = 0; c < NCLS; ++c) acc[c] = make_float4(0.f, 0.f, 0.f, 0.f);

  const size_t base = (size_t)(pg * 4) * CLS_F4 + (size_t)h04 + f;
#pragma unroll
  for (int pp = 0; pp < 4; ++pp) {       // 40 independent float4 loads
#pragma unroll
    for (int c = 0; c < NCLS; ++c) {
      const float4 v = p4[base + (size_t)pp * CLS_F4 + c * HD_F4];
      acc[c].x += v.x; acc[c].y += v.y; acc[c].z += v.z; acc[c].w += v.w;
    }
  }

  // reduce the 8 p-groups within each wave (lane bits 3..5); f preserved
#pragma unroll
  for (int c = 0; c < NCLS; ++c) {
#pragma unroll
    for (int off = 8; off <= 32; off <<= 1) {
      acc[c].x += __shfl_xor(acc[c].x, off, 64);
      acc[c].y += __shfl_xor(acc[c].y, off, 64);
      acc[c].z += __shfl_xor(acc[c].z, off, 64);
      acc[c].w += __shfl_xor(acc[c].w, off, 64);
    }
  }

  __shared__ float4 sred[K2THR / 64][NCLS][8];  // 10 KB
  if (lane < 8) {  // lane == f here
#pragma unroll
    for (int c = 0; c < NCLS; ++c) sred[wave][c][lane] = acc[c];
  }
  __syncthreads();

  __shared__ float4 sS[NCLS][8];
  if (tid < NCLS * 8) {
    const int c = tid >> 3, ff = tid & 7;
    float4 s = sred[0][c][ff];
#pragma unroll
    for (int w = 1; w < K2THR / 64; ++w) {
      const float4 v = sred[w][c][ff];
      s.x += v.x; s.y += v.y; s.z += v.z; s.w += v.w;
    }
    sS[c][ff] = s;
  }
  __syncthreads();

  __shared__ double smm[8], stt[8];
  if (tid < 8) {  // thread per float4 column: squares AFTER full p-sum
    double m = 0.0, t0 = 0.0, t1 = 0.0, t2 = 0.0, t3 = 0.0;
#pragma unroll
    for (int c = 0; c < NCLS; ++c) {
      const float4 s = sS[c][tid];
      m += (double)s.x * s.x + (double)s.y * s.y +
           (double)s.z * s.z + (double)s.w * s.w;
      t0 += s.x; t1 += s.y; t2 += s.z; t3 += s.w;
    }
    smm[tid] = m;
    stt[tid] = t0 * t0 + t1 * t1 + t2 * t2 + t3 * t3;
  }
  __syncthreads();
  if (tid == 0) {
    double m = 0.0, t = 0.0;
#pragma unroll
    for (int i = 0; i < 8; ++i) { m += smm[i]; t += stt[i]; }
    bsums[(size_t)blockIdx.x * 2]     = m;  // sum_c sum_h S_c[h]^2 (stripe)
    bsums[(size_t)blockIdx.x * 2 + 1] = t;  // sum_h (sum_c S_c[h])^2 (stripe)
  }
}

__global__ __launch_bounds__(512) void k3_final(
    const double* __restrict__ bsums, const int* __restrict__ lab,
    float* __restrict__ out, int N) {
  __shared__ int scnt[NCLS];
  const int tid = threadIdx.x, lane = tid & 63;
  if (tid < NCLS) scnt[tid] = 0;
  __syncthreads();

  // label histogram via register counters
  int cnt[NCLS];
#pragma unroll
  for (int c = 0; c < NCLS; ++c) cnt[c] = 0;
  for (int i = tid; i < N; i += blockDim.x) {
    const int l = lab[i];
#pragma unroll
    for (int c = 0; c < NCLS; ++c) cnt[c] += (l == c);
  }
#pragma unroll
  for (int c = 0; c < NCLS; ++c) {
    int v = cnt[c];
#pragma unroll
    for (int off = 32; off >= 1; off >>= 1) v += __shfl_xor(v, off, 64);
    if (lane == 0) atomicAdd(&scnt[c], v);
  }
  __syncthreads();

  if (tid == 0) {
    double m = 0.0, t = 0.0;
#pragma unroll
    for (int b = 0; b < K2BLK; ++b) {  // 48 independent loads, pipelined
      m += bsums[2 * b];
      t += bsums[2 * b + 1];
    }
    double n_pos = 0.0;
    for (int c = 0; c < NCLS; ++c) { const double cc = scnt[c]; n_pos += cc * cc; }
    const double T = 0.07;
    const double nn = (double)N * (double)N;
    const double pos_mean = m / (T * n_pos);
    const double neg_mean = (t - m) / (T * (nn - n_pos));
    const double d = neg_mean - pos_mean;
    out[0] = (float)(fmax(d, 0.0) + log1p(exp(-fabs(d))));  // logaddexp(0,d)
  }
}

extern "C" void kernel_launch(void* const* d_in, const int* in_sizes, int n_in,
                              void* d_out, int out_size, void* d_ws, size_t ws_size,
                              hipStream_t stream) {
  const float* x = (const float*)d_in[0];
  const int* lab = (const int*)d_in[1];
  const int N = in_sizes[1];  // 8192 = PBLK * RPB (fixed problem shape)

  float* partials = (float*)d_ws;  // 256*7680 floats = 7.86 MB
  double* bsums = (double*)(partials + (size_t)PBLK * CLS_FLOATS);  // 48 doubles

  k1_fused<<<PBLK, HDIM, 0, stream>>>(x, lab, partials);
  k2_full<<<K2BLK, K2THR, 0, stream>>>(partials, bsums);
  k3_final<<<1, 512, 0, stream>>>(bsums, lab, (float*)d_out, N);
}